// Round 1
// baseline (4932.863 us; speedup 1.0000x reference)
//
#include <hip/hip_runtime.h>
#include <hip/hip_bf16.h>

#define VOCAB 100
#define EMB   32
#define HID   64
#define G4    256   // 4*HID, gate count
#define TT    200
#define BATCH 8192
#define NOUT  32
#define BTILE 16

__device__ __forceinline__ float sigmoidf_(float x) {
    return 1.0f / (1.0f + __expf(-x));
}
__device__ __forceinline__ float tanhf_(float x) {
    // tanh(x) = 1 - 2/(1+exp(2x)); saturates correctly for |x| large
    return 1.0f - 2.0f / (1.0f + __expf(2.0f * x));
}

// ---------------- LUT precompute: lut[v][j] = bih0[j]+bhh0[j] + sum_k emb[v][k]*Wih0[j][k]
__global__ void build_lut(const float* __restrict__ emb, const float* __restrict__ Wih0,
                          const float* __restrict__ bih0, const float* __restrict__ bhh0,
                          float* __restrict__ lut) {
    const int v = blockIdx.x;
    const int j = threadIdx.x;
    const float* e = emb + v * EMB;
    const float* w = Wih0 + j * EMB;
    float s = bih0[j] + bhh0[j];
#pragma unroll
    for (int k = 0; k < EMB; ++k) s = fmaf(e[k], w[k], s);
    lut[v * G4 + j] = s;
}

// ---------------- Fused 2-layer LSTM over all T steps + FC epilogue
__global__ __launch_bounds__(256, 4) void lstm_main(
    const int*   __restrict__ x,
    const float* __restrict__ Whh0,
    const float* __restrict__ Wih1,
    const float* __restrict__ Whh1,
    const float* __restrict__ bih1,
    const float* __restrict__ bhh1,
    const float* __restrict__ Wfc,
    const float* __restrict__ bfc,
    const float* __restrict__ lut,
    float* __restrict__ out) {

    __shared__ __align__(16) float h0s[BTILE * HID];   // 4 KB
    __shared__ __align__(16) float h1s[BTILE * HID];   // 4 KB
    __shared__ __align__(16) float gs[BTILE * G4];     // 16 KB
    __shared__ int xs[BTILE * TT];                     // 12.8 KB

    const int tid = threadIdx.x;
    const int wg  = blockIdx.x;
    const int r0  = wg * BTILE;

    // preload x tile (x is (B,T) row-major -> linear copy)
    for (int i = tid; i < BTILE * TT; i += 256) xs[i] = x[r0 * TT + i];
    // zero h state
    for (int i = tid; i < BTILE * HID; i += 256) { h0s[i] = 0.0f; h1s[i] = 0.0f; }
    __syncthreads();

    // matvec mapping: thread -> gate pair (j0, j0+128) x 8 rows
    const int jj = tid & 127;
    const int rg = tid >> 7;       // 0/1 row-group
    const int j0 = jj;
    const int j1 = jj + 128;
    const int rb = rg * 8;

    // cell-update mapping: thread -> unit uu x 4 rows
    const int uu = tid & 63;
    const int rs = tid >> 6;       // 0..3
    float c0r[4] = {0.f, 0.f, 0.f, 0.f};
    float c1r[4] = {0.f, 0.f, 0.f, 0.f};

    const float bias1_0 = bih1[j0] + bhh1[j0];
    const float bias1_1 = bih1[j1] + bhh1[j1];

    for (int t = 0; t < TT; ++t) {
        // ---- Phase A: gates0 = lut[x[r][t]] + Whh0 * h0 ----
        float acc0[8], acc1[8];
#pragma unroll
        for (int i = 0; i < 8; ++i) {
            const int xv = xs[(rb + i) * TT + t];
            acc0[i] = lut[xv * G4 + j0];
            acc1[i] = lut[xv * G4 + j1];
        }
#pragma unroll 2
        for (int kk = 0; kk < HID / 4; ++kk) {
            const float4 wa = *reinterpret_cast<const float4*>(Whh0 + j0 * HID + kk * 4);
            const float4 wb = *reinterpret_cast<const float4*>(Whh0 + j1 * HID + kk * 4);
#pragma unroll
            for (int i = 0; i < 8; ++i) {
                const float4 h4 = *reinterpret_cast<const float4*>(h0s + (rb + i) * HID + kk * 4);
                acc0[i] = fmaf(wa.x, h4.x, fmaf(wa.y, h4.y, fmaf(wa.z, h4.z, fmaf(wa.w, h4.w, acc0[i]))));
                acc1[i] = fmaf(wb.x, h4.x, fmaf(wb.y, h4.y, fmaf(wb.z, h4.z, fmaf(wb.w, h4.w, acc1[i]))));
            }
        }
#pragma unroll
        for (int i = 0; i < 8; ++i) {
            gs[(rb + i) * G4 + j0] = acc0[i];
            gs[(rb + i) * G4 + j1] = acc1[i];
        }
        __syncthreads();

        // ---- Phase B: LSTM0 cell update, write h0 ----
#pragma unroll
        for (int m = 0; m < 4; ++m) {
            const int r = rs * 4 + m;
            const float ig = sigmoidf_(gs[r * G4 + uu]);
            const float fg = sigmoidf_(gs[r * G4 + uu + 64]);
            const float gg = tanhf_(gs[r * G4 + uu + 128]);
            const float og = sigmoidf_(gs[r * G4 + uu + 192]);
            const float c  = fg * c0r[m] + ig * gg;
            c0r[m] = c;
            h0s[r * HID + uu] = og * tanhf_(c);
        }
        __syncthreads();

        // ---- Phase C: gates1 = bias1 + Wih1*h0new + Whh1*h1 ----
        float a0[8], a1[8];
#pragma unroll
        for (int i = 0; i < 8; ++i) { a0[i] = bias1_0; a1[i] = bias1_1; }
#pragma unroll 2
        for (int kk = 0; kk < HID / 4; ++kk) {
            const float4 wa = *reinterpret_cast<const float4*>(Wih1 + j0 * HID + kk * 4);
            const float4 wb = *reinterpret_cast<const float4*>(Wih1 + j1 * HID + kk * 4);
#pragma unroll
            for (int i = 0; i < 8; ++i) {
                const float4 h4 = *reinterpret_cast<const float4*>(h0s + (rb + i) * HID + kk * 4);
                a0[i] = fmaf(wa.x, h4.x, fmaf(wa.y, h4.y, fmaf(wa.z, h4.z, fmaf(wa.w, h4.w, a0[i]))));
                a1[i] = fmaf(wb.x, h4.x, fmaf(wb.y, h4.y, fmaf(wb.z, h4.z, fmaf(wb.w, h4.w, a1[i]))));
            }
        }
#pragma unroll 2
        for (int kk = 0; kk < HID / 4; ++kk) {
            const float4 wa = *reinterpret_cast<const float4*>(Whh1 + j0 * HID + kk * 4);
            const float4 wb = *reinterpret_cast<const float4*>(Whh1 + j1 * HID + kk * 4);
#pragma unroll
            for (int i = 0; i < 8; ++i) {
                const float4 h4 = *reinterpret_cast<const float4*>(h1s + (rb + i) * HID + kk * 4);
                a0[i] = fmaf(wa.x, h4.x, fmaf(wa.y, h4.y, fmaf(wa.z, h4.z, fmaf(wa.w, h4.w, a0[i]))));
                a1[i] = fmaf(wb.x, h4.x, fmaf(wb.y, h4.y, fmaf(wb.z, h4.z, fmaf(wb.w, h4.w, a1[i]))));
            }
        }
#pragma unroll
        for (int i = 0; i < 8; ++i) {
            gs[(rb + i) * G4 + j0] = a0[i];
            gs[(rb + i) * G4 + j1] = a1[i];
        }
        __syncthreads();

        // ---- Phase D: LSTM1 cell update, write h1 ----
#pragma unroll
        for (int m = 0; m < 4; ++m) {
            const int r = rs * 4 + m;
            const float ig = sigmoidf_(gs[r * G4 + uu]);
            const float fg = sigmoidf_(gs[r * G4 + uu + 64]);
            const float gg = tanhf_(gs[r * G4 + uu + 128]);
            const float og = sigmoidf_(gs[r * G4 + uu + 192]);
            const float c  = fg * c1r[m] + ig * gg;
            c1r[m] = c;
            h1s[r * HID + uu] = og * tanhf_(c);
        }
        __syncthreads();
    }

    // ---- FC epilogue: out = relu(h1 @ Wfc.T + bfc), 16 rows x 32 outs = 512 jobs ----
#pragma unroll
    for (int s = 0; s < 2; ++s) {
        const int job = tid + s * 256;
        const int r = job >> 5;
        const int o = job & 31;
        float acc = bfc[o];
        const float* wf = Wfc + o * HID;
#pragma unroll
        for (int k = 0; k < HID / 4; ++k) {
            const float4 w4 = *reinterpret_cast<const float4*>(wf + k * 4);
            const float4 h4 = *reinterpret_cast<const float4*>(h1s + r * HID + k * 4);
            acc = fmaf(w4.x, h4.x, fmaf(w4.y, h4.y, fmaf(w4.z, h4.z, fmaf(w4.w, h4.w, acc))));
        }
        out[(r0 + r) * NOUT + o] = fmaxf(acc, 0.0f);
    }
}

extern "C" void kernel_launch(void* const* d_in, const int* in_sizes, int n_in,
                              void* d_out, int out_size, void* d_ws, size_t ws_size,
                              hipStream_t stream) {
    const int*   x    = (const int*)  d_in[0];
    const float* emb  = (const float*)d_in[1];
    const float* Wih0 = (const float*)d_in[2];
    const float* Whh0 = (const float*)d_in[3];
    const float* bih0 = (const float*)d_in[4];
    const float* bhh0 = (const float*)d_in[5];
    const float* Wih1 = (const float*)d_in[6];
    const float* Whh1 = (const float*)d_in[7];
    const float* bih1 = (const float*)d_in[8];
    const float* bhh1 = (const float*)d_in[9];
    const float* Wfc  = (const float*)d_in[10];
    const float* bfc  = (const float*)d_in[11];
    float* out = (float*)d_out;
    float* lut = (float*)d_ws;   // 100*256*4 = 102,400 bytes

    hipLaunchKernelGGL(build_lut, dim3(VOCAB), dim3(G4), 0, stream,
                       emb, Wih0, bih0, bhh0, lut);
    hipLaunchKernelGGL(lstm_main, dim3(BATCH / BTILE), dim3(256), 0, stream,
                       x, Whh0, Wih1, Whh1, bih1, bhh1, Wfc, bfc, lut, out);
}

// Round 2
// 936.456 us; speedup vs baseline: 5.2676x; 5.2676x over previous
//
#include <hip/hip_runtime.h>
#include <hip/hip_bf16.h>

#define VOCAB 100
#define EMB   32
#define HID   64
#define G4    256
#define TT    200
#define BATCH 8192
#define NOUT  32
#define BT    16    // batch rows per WG

typedef __attribute__((ext_vector_type(8))) short short8;
typedef __attribute__((ext_vector_type(4))) float floatx4;

__device__ __forceinline__ unsigned short f2bf(float x) {
    unsigned int b = __float_as_uint(x);
    b += 0x7FFFu + ((b >> 16) & 1u);          // round-to-nearest-even
    return (unsigned short)(b >> 16);
}
__device__ __forceinline__ float bf2f(unsigned short u) {
    return __uint_as_float(((unsigned int)u) << 16);
}
__device__ __forceinline__ float sigf(float x) {
    return __builtin_amdgcn_rcpf(1.0f + exp2f(x * -1.4426950408889634f));
}
__device__ __forceinline__ float tanhf_(float x) {
    return 1.0f - 2.0f * __builtin_amdgcn_rcpf(1.0f + exp2f(x * 2.8853900817779268f));
}
__device__ __forceinline__ void split8(const float* __restrict__ src, short8& hi, short8& lo) {
#pragma unroll
    for (int j = 0; j < 8; ++j) {
        float w = src[j];
        unsigned short h = f2bf(w);
        unsigned short l = f2bf(w - bf2f(h));
        hi[j] = (short)h;
        lo[j] = (short)l;
    }
}

// lut[v][unit][gate] (gate-minor float4) = bih0+bhh0 + emb[v] . Wih0-row
__global__ void build_lut(const float* __restrict__ emb, const float* __restrict__ Wih0,
                          const float* __restrict__ bih0, const float* __restrict__ bhh0,
                          float* __restrict__ lut) {
    const int v = blockIdx.x;
    const int j = threadIdx.x;              // gate index 0..255
    const float* e = emb + v * EMB;
    const float* w = Wih0 + j * EMB;
    float s = bih0[j] + bhh0[j];
#pragma unroll
    for (int k = 0; k < EMB; ++k) s = fmaf(e[k], w[k], s);
    lut[v * G4 + (j & 63) * 4 + (j >> 6)] = s;   // unit-major, gate-minor
}

// Fused 2-layer LSTM, split-bf16 MFMA. Wave q owns col-tiles {q,q+4,q+8,q+12}.
__global__ __launch_bounds__(256, 1) void lstm_mfma(
    const int*   __restrict__ x,
    const float* __restrict__ Whh0,
    const float* __restrict__ Wih1,
    const float* __restrict__ Whh1,
    const float* __restrict__ bih1,
    const float* __restrict__ bhh1,
    const float* __restrict__ Wfc,
    const float* __restrict__ bfc,
    const float* __restrict__ lut,
    float* __restrict__ out) {

    // h planes: [16 rows][128 k] bf16; k 0-63 = h0, 64-127 = h1.
    // 16B-chunk XOR swizzle: chunk' = chunk ^ (row & 7)  (bank-conflict-free b128 reads)
    __shared__ __align__(16) unsigned short hHI[BT * 128];
    __shared__ __align__(16) unsigned short hLO[BT * 128];
    __shared__ int xs[BT * TT];

    const int tid  = threadIdx.x;
    const int lane = tid & 63;
    const int q    = tid >> 6;          // wave id = col-tile quarter
    const int r0   = blockIdx.x * BT;

    for (int i = tid; i < BT * TT; i += 256) xs[i] = x[r0 * TT + i];
    for (int i = tid; i < BT * 128; i += 256) { hHI[i] = 0; hLO[i] = 0; }

    const int mcol = lane & 15;         // A-row / D-col / B-col index
    const int lkb  = lane >> 4;         // k-block-of-8 selector
    const int u    = q * 16 + mcol;     // hidden unit owned for cell updates

    // ---- preload weight B-frags (hi/lo split) into registers ----
    short8 w0h[4][2], w0l[4][2], w1h[4][4], w1l[4][4];
    float  b1v[4];
#pragma unroll
    for (int ci = 0; ci < 4; ++ci) {
        const int ct = q + ci * 4;           // ci: 0=i,1=f,2=g,3=o tile
        const int jw = ct * 16 + mcol;       // output gate row of W
#pragma unroll
        for (int kb = 0; kb < 2; ++kb)
            split8(Whh0 + jw * HID + kb * 32 + lkb * 8, w0h[ci][kb], w0l[ci][kb]);
#pragma unroll
        for (int kb = 0; kb < 4; ++kb) {
            const int k = kb * 32 + lkb * 8;  // K=128 = [h0 | h1]
            const float* src = (k < 64) ? (Wih1 + jw * HID + k)
                                        : (Whh1 + jw * HID + (k - 64));
            split8(src, w1h[ci][kb], w1l[ci][kb]);
        }
        b1v[ci] = bih1[jw] + bhh1[jw];
    }

    float c0[4] = {0.f, 0.f, 0.f, 0.f};
    float c1[4] = {0.f, 0.f, 0.f, 0.f};

    __syncthreads();

    const float4* lut4 = reinterpret_cast<const float4*>(lut);

    for (int t = 0; t < TT; ++t) {
        // ---- LUT gather (layer0 input proj + bias), one float4 per row ----
        float lv[4][4];
#pragma unroll
        for (int m = 0; m < 4; ++m) {
            const int r  = lkb * 4 + m;
            const int xv = xs[r * TT + t];
            const float4 g = lut4[xv * 64 + u];
            lv[m][0] = g.x; lv[m][1] = g.y; lv[m][2] = g.z; lv[m][3] = g.w;
        }

        // ---- Phase A: gates0 = Whh0 * h0  (split bf16, K=64) ----
        short8 ah0, ah1, alo0, alo1;
        {
            const int cs0 = (0 * 4 + lkb) ^ (mcol & 7);
            const int cs1 = (1 * 4 + lkb) ^ (mcol & 7);
            ah0  = *reinterpret_cast<const short8*>(&hHI[mcol * 128 + cs0 * 8]);
            ah1  = *reinterpret_cast<const short8*>(&hHI[mcol * 128 + cs1 * 8]);
            alo0 = *reinterpret_cast<const short8*>(&hLO[mcol * 128 + cs0 * 8]);
            alo1 = *reinterpret_cast<const short8*>(&hLO[mcol * 128 + cs1 * 8]);
        }
        floatx4 g0[4];
#pragma unroll
        for (int ci = 0; ci < 4; ++ci) {
            floatx4 d = {0.f, 0.f, 0.f, 0.f};
            d = __builtin_amdgcn_mfma_f32_16x16x32_bf16(ah0,  w0h[ci][0], d, 0, 0, 0);
            d = __builtin_amdgcn_mfma_f32_16x16x32_bf16(ah1,  w0h[ci][1], d, 0, 0, 0);
            d = __builtin_amdgcn_mfma_f32_16x16x32_bf16(alo0, w0h[ci][0], d, 0, 0, 0);
            d = __builtin_amdgcn_mfma_f32_16x16x32_bf16(alo1, w0h[ci][1], d, 0, 0, 0);
            d = __builtin_amdgcn_mfma_f32_16x16x32_bf16(ah0,  w0l[ci][0], d, 0, 0, 0);
            d = __builtin_amdgcn_mfma_f32_16x16x32_bf16(ah1,  w0l[ci][1], d, 0, 0, 0);
            g0[ci] = d;
        }
        __syncthreads();   // A-reads of h0[t-1] done before B overwrites

        // ---- Phase B: layer0 cell update (in-register), write h0 hi/lo ----
#pragma unroll
        for (int m = 0; m < 4; ++m) {
            const float gi = g0[0][m] + lv[m][0];
            const float gf = g0[1][m] + lv[m][1];
            const float gg = g0[2][m] + lv[m][2];
            const float go = g0[3][m] + lv[m][3];
            const float c  = sigf(gf) * c0[m] + sigf(gi) * tanhf_(gg);
            c0[m] = c;
            const float h  = sigf(go) * tanhf_(c);
            const unsigned short hi = f2bf(h);
            const unsigned short lo = f2bf(h - bf2f(hi));
            const int r   = lkb * 4 + m;
            const int cs  = (u >> 3) ^ (r & 7);
            const int idx = r * 128 + cs * 8 + (u & 7);
            hHI[idx] = hi; hLO[idx] = lo;
        }
        __syncthreads();   // B-writes visible before C reads

        // ---- Phase C: gates1 = b1 + [Wih1|Whh1] * [h0|h1]  (K=128) ----
        short8 af[4];
#pragma unroll
        for (int kb = 0; kb < 4; ++kb) {
            const int cs = (kb * 4 + lkb) ^ (mcol & 7);
            af[kb] = *reinterpret_cast<const short8*>(&hHI[mcol * 128 + cs * 8]);
        }
        floatx4 g1[4];
#pragma unroll
        for (int ci = 0; ci < 4; ++ci) {
            floatx4 d = {b1v[ci], b1v[ci], b1v[ci], b1v[ci]};
#pragma unroll
            for (int kb = 0; kb < 4; ++kb)
                d = __builtin_amdgcn_mfma_f32_16x16x32_bf16(af[kb], w1h[ci][kb], d, 0, 0, 0);
#pragma unroll
            for (int kb = 0; kb < 4; ++kb)
                d = __builtin_amdgcn_mfma_f32_16x16x32_bf16(af[kb], w1l[ci][kb], d, 0, 0, 0);
            g1[ci] = d;
        }
#pragma unroll
        for (int kb = 0; kb < 4; ++kb) {
            const int cs = (kb * 4 + lkb) ^ (mcol & 7);
            af[kb] = *reinterpret_cast<const short8*>(&hLO[mcol * 128 + cs * 8]);
        }
#pragma unroll
        for (int ci = 0; ci < 4; ++ci) {
            floatx4 d = g1[ci];
#pragma unroll
            for (int kb = 0; kb < 4; ++kb)
                d = __builtin_amdgcn_mfma_f32_16x16x32_bf16(af[kb], w1h[ci][kb], d, 0, 0, 0);
            g1[ci] = d;
        }
        __syncthreads();   // C-reads of h1[t-1] done before D overwrites

        // ---- Phase D: layer1 cell update, write h1 (chunks 8-15; disjoint
        //      from next phase-A reads/phase-B writes -> no barrier needed) ----
#pragma unroll
        for (int m = 0; m < 4; ++m) {
            const float gi = g1[0][m];
            const float gf = g1[1][m];
            const float gg = g1[2][m];
            const float go = g1[3][m];
            const float c  = sigf(gf) * c1[m] + sigf(gi) * tanhf_(gg);
            c1[m] = c;
            const float h  = sigf(go) * tanhf_(c);
            const unsigned short hi = f2bf(h);
            const unsigned short lo = f2bf(h - bf2f(hi));
            const int r   = lkb * 4 + m;
            const int cs  = (8 + (u >> 3)) ^ (r & 7);
            const int idx = r * 128 + cs * 8 + (u & 7);
            hHI[idx] = hi; hLO[idx] = lo;
        }
    }
    __syncthreads();

    // ---- FC epilogue: out = relu(h1_last @ Wfc.T + bfc) ----
#pragma unroll
    for (int s = 0; s < 2; ++s) {
        const int job = tid + s * 256;
        const int r = job >> 5;
        const int o = job & 31;
        float acc = bfc[o];
#pragma unroll
        for (int uu = 0; uu < HID; ++uu) {
            const int cs  = (8 + (uu >> 3)) ^ (r & 7);
            const int idx = r * 128 + cs * 8 + (uu & 7);
            const float hv = bf2f(hHI[idx]) + bf2f(hLO[idx]);
            acc = fmaf(hv, Wfc[o * HID + uu], acc);
        }
        out[(r0 + r) * NOUT + o] = fmaxf(acc, 0.f);
    }
}

extern "C" void kernel_launch(void* const* d_in, const int* in_sizes, int n_in,
                              void* d_out, int out_size, void* d_ws, size_t ws_size,
                              hipStream_t stream) {
    const int*   x    = (const int*)  d_in[0];
    const float* emb  = (const float*)d_in[1];
    const float* Wih0 = (const float*)d_in[2];
    const float* Whh0 = (const float*)d_in[3];
    const float* bih0 = (const float*)d_in[4];
    const float* bhh0 = (const float*)d_in[5];
    const float* Wih1 = (const float*)d_in[6];
    const float* Whh1 = (const float*)d_in[7];
    const float* bih1 = (const float*)d_in[8];
    const float* bhh1 = (const float*)d_in[9];
    const float* Wfc  = (const float*)d_in[10];
    const float* bfc  = (const float*)d_in[11];
    float* out = (float*)d_out;
    float* lut = (float*)d_ws;   // 100*256*4 = 102,400 bytes

    hipLaunchKernelGGL(build_lut, dim3(VOCAB), dim3(G4), 0, stream,
                       emb, Wih0, bih0, bhh0, lut);
    hipLaunchKernelGGL(lstm_mfma, dim3(BATCH / BT), dim3(256), 0, stream,
                       x, Whh0, Wih1, Whh1, bih1, bhh1, Wfc, bfc, lut, out);
}